// Round 2
// baseline (162.950 us; speedup 1.0000x reference)
//
#include <hip/hip_runtime.h>

constexpr int TPB = 256;

__device__ __forceinline__ float fast_tanh(float v) {
    // tanh(x) = 1 - 2/(exp(2x)+1); exact at +/-inf, ~ulp-level error
    float ex = __expf(2.0f * v);
    return 1.0f - 2.0f * __builtin_amdgcn_rcpf(ex + 1.0f);
}

// triangle index for symmetric 4x4: requires a <= b
#define TRI(a, b) ((a) * 4 + (b) - ((a) * ((a) + 1)) / 2)

__device__ __forceinline__ void load_chunk(const float* __restrict__ xu,
                                           const float* __restrict__ xv,
                                           int c, float (&u)[4][4], float (&v)[4][4]) {
    #pragma unroll
    for (int d = 0; d < 4; ++d) {
        float4 a = *(const float4*)(xu + d * 32 + c * 4);
        float4 b = *(const float4*)(xv + d * 32 + c * 4);
        u[d][0] = a.x; u[d][1] = a.y; u[d][2] = a.z; u[d][3] = a.w;
        v[d][0] = b.x; v[d][1] = b.y; v[d][2] = b.z; v[d][3] = b.w;
    }
}

__device__ __forceinline__ void compute_chunk(const float (&u)[4][4], const float (&v)[4][4],
                                              float (&Gu)[10], float (&Gv)[10], float (&C)[16]) {
    // symmetric grams: only d<=k
    #pragma unroll
    for (int d = 0; d < 4; ++d) {
        #pragma unroll
        for (int k = d; k < 4; ++k) {
            float au = Gu[TRI(d, k)], av = Gv[TRI(d, k)];
            #pragma unroll
            for (int j = 0; j < 4; ++j) {
                au = fmaf(u[d][j], u[k][j], au);
                av = fmaf(v[d][j], v[k][j], av);
            }
            Gu[TRI(d, k)] = au; Gv[TRI(d, k)] = av;
        }
    }
    // cross gram C[d][k] = sum_h v[d][h] * u[k][h]
    #pragma unroll
    for (int d = 0; d < 4; ++d) {
        #pragma unroll
        for (int k = 0; k < 4; ++k) {
            float ac = C[d * 4 + k];
            #pragma unroll
            for (int j = 0; j < 4; ++j) ac = fmaf(v[d][j], u[k][j], ac);
            C[d * 4 + k] = ac;
        }
    }
}

// symmetric fetch with unrolled (compile-time) indices
#define GSYM(G, a, b) ((a) <= (b) ? G[TRI(a, b)] : G[TRI(b, a)])

__global__ __launch_bounds__(TPB) void sheaf_lane_kernel(
    const float* __restrict__ x,          // (N, 4, 32)
    const float* __restrict__ Maps,       // (E, 4, 4)
    const float* __restrict__ W1,         // (16, 16)
    const float* __restrict__ b1,         // (16,)
    const int*   __restrict__ edge_index, // (2, E)
    const int*   __restrict__ opp_idx,    // (E,)
    float*       __restrict__ out,        // (E, 4, 4)
    int E, int EHALF)
{
    const int pair = blockIdx.x * TPB + threadIdx.x;
    if (pair >= EHALF) return;

    const int s  = edge_index[pair];
    const int t  = edge_index[E + pair];
    const int e2 = opp_idx[pair];

    const float* __restrict__ xu = x + (size_t)s * 128;
    const float* __restrict__ xv = x + (size_t)t * 128;

    float Gu[10], Gv[10], C[16];
    #pragma unroll
    for (int i = 0; i < 10; ++i) { Gu[i] = 0.f; Gv[i] = 0.f; }
    #pragma unroll
    for (int i = 0; i < 16; ++i) C[i] = 0.f;

    // 8 chunks of 4 h-columns, explicit 2-deep A/B load pipeline (static bufs)
    float uA[4][4], vA[4][4], uB[4][4], vB[4][4];
    load_chunk(xu, xv, 0, uA, vA);
    #pragma unroll
    for (int c = 0; c < 8; ++c) {
        if ((c & 1) == 0) {
            if (c < 7) load_chunk(xu, xv, c + 1, uB, vB);
            compute_chunk(uA, vA, Gu, Gv, C);
        } else {
            if (c < 7) load_chunk(xu, xv, c + 1, uA, vA);
            compute_chunk(uB, vB, Gu, Gv, C);
        }
    }

    // Maps for both orientations (coalesced: lane's pair index is contiguous)
    float4 m1[4], m2[4];
    #pragma unroll
    for (int i = 0; i < 4; ++i) {
        m1[i] = *(const float4*)(Maps + (size_t)pair * 16 + i * 4);
        m2[i] = *(const float4*)(Maps + (size_t)e2   * 16 + i * 4);
    }

    // sims for both edge orientations, fully in registers
    float s1[16], s2[16];
    #pragma unroll
    for (int i = 0; i < 4; ++i) {
        #pragma unroll
        for (int k = 0; k < 4; ++k) {
            // sims1[i][k] = 2*( M1[i,:].Gu[:,k] - M2[i,:].C[:,k] )
            float gss = m1[i].x * GSYM(Gu, 0, k) + m1[i].y * GSYM(Gu, 1, k)
                      + m1[i].z * GSYM(Gu, 2, k) + m1[i].w * GSYM(Gu, 3, k);
            float gts = m2[i].x * C[0 * 4 + k] + m2[i].y * C[1 * 4 + k]
                      + m2[i].z * C[2 * 4 + k] + m2[i].w * C[3 * 4 + k];
            s1[i * 4 + k] = 2.0f * (gss - gts);
            // sims2[i][k] = 2*( M2[i,:].Gv[:,k] - M1[i,:].C[k,:] )   (C^T term)
            float gss2 = m2[i].x * GSYM(Gv, 0, k) + m2[i].y * GSYM(Gv, 1, k)
                       + m2[i].z * GSYM(Gv, 2, k) + m2[i].w * GSYM(Gv, 3, k);
            float gts2 = m1[i].x * C[k * 4 + 0] + m1[i].y * C[k * 4 + 1]
                       + m1[i].z * C[k * 4 + 2] + m1[i].w * C[k * 4 + 3];
            s2[i * 4 + k] = 2.0f * (gss2 - gts2);
        }
    }

    // linear (y = sims @ W1^T + b1) + tanh; W1/b1 are lane-uniform -> scalar cache
    float r1[16], r2[16];
    #pragma unroll
    for (int p = 0; p < 16; ++p) {
        float bb = b1[p];
        float a1 = bb, a2 = bb;
        #pragma unroll
        for (int q = 0; q < 16; ++q) {
            float w = W1[p * 16 + q];
            a1 = fmaf(w, s1[q], a1);
            a2 = fmaf(w, s2[q], a2);
        }
        r1[p] = fast_tanh(a1);
        r2[p] = fast_tanh(a2);
    }

    float* o1 = out + (size_t)pair * 16;
    float* o2 = out + (size_t)e2   * 16;
    #pragma unroll
    for (int q4 = 0; q4 < 4; ++q4) {
        *(float4*)(o1 + q4 * 4) = make_float4(r1[q4 * 4], r1[q4 * 4 + 1], r1[q4 * 4 + 2], r1[q4 * 4 + 3]);
        *(float4*)(o2 + q4 * 4) = make_float4(r2[q4 * 4], r2[q4 * 4 + 1], r2[q4 * 4 + 2], r2[q4 * 4 + 3]);
    }
}

extern "C" void kernel_launch(void* const* d_in, const int* in_sizes, int n_in,
                              void* d_out, int out_size, void* d_ws, size_t ws_size,
                              hipStream_t stream) {
    const float* x          = (const float*)d_in[0];
    const float* Maps       = (const float*)d_in[1];
    const float* W1         = (const float*)d_in[2];
    const float* b1         = (const float*)d_in[3];
    const int*   edge_index = (const int*)d_in[4];
    const int*   opp_idx    = (const int*)d_in[5];

    const int E     = in_sizes[5];
    const int EHALF = E / 2;

    const int blocks = (EHALF + TPB - 1) / TPB;
    sheaf_lane_kernel<<<blocks, TPB, 0, stream>>>(
        x, Maps, W1, b1, edge_index, opp_idx, (float*)d_out, E, EHALF);
}

// Round 3
// 81.756 us; speedup vs baseline: 1.9931x; 1.9931x over previous
//
#include <hip/hip_runtime.h>

constexpr int GROUPS    = 16;             // pairs (or nodes) per 256-thread block
constexpr int XSTRIDE   = 36;             // padded row stride in words (H=32 + 4)
constexpr int XROW      = 4 * XSTRIDE;    // 144 words per node
constexpr int GBUF      = 2 * XROW + 8;   // 296 words per group (proven round-1 layout)
constexpr int GRAMS     = 52;             // Gs[16] Gt[16] C[16] + pad
constexpr int SIMSTRIDE = 40;             // s1[16] s2[16] + pad

__device__ __forceinline__ float fast_tanh(float v) {
    // tanh(x) = 1 - 2/(exp(2x)+1); exact at +/-inf, ~ulp-level error
    float ex = __expf(2.0f * v);
    return 1.0f - 2.0f * __builtin_amdgcn_rcpf(ex + 1.0f);
}

// ---------------- K1: per-node gram  G_n = X_n X_n^T  (16 lanes per node) ----
__global__ __launch_bounds__(256) void node_gram_kernel(
    const float* __restrict__ x, float* __restrict__ G, int N)
{
    const int tid = threadIdx.x;
    const int g = tid >> 4, l = tid & 15;
    const int node = blockIdx.x * GROUPS + g;
    if (node >= N) return;
    const int d = l >> 2, k = l & 3;
    const float* xr = x + (size_t)node * 128;
    float4 acc = {0.f, 0.f, 0.f, 0.f};
    #pragma unroll
    for (int c = 0; c < 8; ++c) {
        float4 a = *(const float4*)(xr + d * 32 + c * 4);   // row d (4-way lane broadcast)
        float4 b = *(const float4*)(xr + k * 32 + c * 4);   // row k
        acc.x = fmaf(a.x, b.x, acc.x); acc.y = fmaf(a.y, b.y, acc.y);
        acc.z = fmaf(a.z, b.z, acc.z); acc.w = fmaf(a.w, b.w, acc.w);
    }
    G[(size_t)node * 16 + l] = acc.x + acc.y + acc.z + acc.w;  // coalesced 64B/group
}

// ---------------- K2: per-pair kernel (16 lanes per undirected pair) ---------
// PRE=true: node grams from G workspace; PRE=false: compute Gu,Gv in-pair.
template <bool PRE>
__global__ __launch_bounds__(256) void sheaf_pair2_kernel(
    const float* __restrict__ x,          // (N, 4, 32)
    const float* __restrict__ Maps,       // (E, 4, 4)
    const float* __restrict__ W1,         // (16, 16)
    const float* __restrict__ b1,         // (16,)
    const int*   __restrict__ edge_index, // (2, E)
    const int*   __restrict__ opp_idx,    // (E,)
    const float* __restrict__ G,          // (N, 16) node grams (if PRE)
    float*       __restrict__ out,        // (E, 4, 4)
    int E, int EHALF)
{
    __shared__ __align__(16) float xbuf[GROUPS * GBUF];
    __shared__ __align__(16) float gram[GROUPS * GRAMS];
    __shared__ __align__(16) float simsb[GROUPS * SIMSTRIDE];

    const int tid = threadIdx.x;
    const int g  = tid >> 4;
    const int l  = tid & 15;
    const int di = l >> 2;
    const int kj = l & 3;

    const int pair  = blockIdx.x * GROUPS + g;
    const bool valid = pair < EHALF;

    // lane-owned W1 row + bias (L1-cached, identical across groups/blocks)
    const float4* Wp = (const float4*)(W1 + l * 16);
    float4 w0 = Wp[0], w1 = Wp[1], w2 = Wp[2], w3 = Wp[3];
    float bias = b1[l];

    int s = 0, t = 0, e2 = 0;
    if (valid) {
        s  = edge_index[pair];
        t  = edge_index[E + pair];
        e2 = opp_idx[pair];
    }

    float* xg = xbuf + g * GBUF;
    float* gr = gram + g * GRAMS;

    if (valid) {
        // cooperative coalesced stage of x[s], x[t] (lane l: d=l>>2, h0=(l&3)*8)
        const float4* xs = (const float4*)(x + (size_t)s * 128);
        const float4* xt = (const float4*)(x + (size_t)t * 128);
        const int d0 = l >> 2, h0 = (l & 3) * 8;
        float4 a0 = xs[l * 2];
        float4 a1 = xs[l * 2 + 1];
        float4 c0 = xt[l * 2];
        float4 c1 = xt[l * 2 + 1];
        *(float4*)(xg + d0 * XSTRIDE + h0)            = a0;
        *(float4*)(xg + d0 * XSTRIDE + h0 + 4)        = a1;
        *(float4*)(xg + XROW + d0 * XSTRIDE + h0)     = c0;
        *(float4*)(xg + XROW + d0 * XSTRIDE + h0 + 4) = c1;
        if (PRE) {
            gr[l]      = G[(size_t)s * 16 + l];   // Gs (symmetric)
            gr[16 + l] = G[(size_t)t * 16 + l];   // Gt (symmetric)
        }
    }

    // hoist Maps rows (latency hidden under the gram loop)
    float4 m1 = {0,0,0,0}, m2 = {0,0,0,0};
    if (valid) {
        m1 = *(const float4*)(Maps + (size_t)pair * 16 + di * 4);
        m2 = *(const float4*)(Maps + (size_t)e2   * 16 + di * 4);
    }

    __syncthreads();

    if (valid) {
        const float* xu = xg;          // x[s]
        const float* xv = xg + XROW;   // x[t]
        if (PRE) {
            // cross gram only: C[di][kj] = sum_h xv[di][h] * xu[kj][h]
            float4 acc = {0,0,0,0};
            #pragma unroll
            for (int c = 0; c < 8; ++c) {
                float4 vd = *(const float4*)(xv + di * XSTRIDE + c * 4);
                float4 uk = *(const float4*)(xu + kj * XSTRIDE + c * 4);
                acc.x = fmaf(vd.x, uk.x, acc.x); acc.y = fmaf(vd.y, uk.y, acc.y);
                acc.z = fmaf(vd.z, uk.z, acc.z); acc.w = fmaf(vd.w, uk.w, acc.w);
            }
            gr[32 + l] = acc.x + acc.y + acc.z + acc.w;
        } else {
            float4 aU = {0,0,0,0}, aV = {0,0,0,0}, aC = {0,0,0,0};
            #pragma unroll
            for (int c = 0; c < 8; ++c) {
                float4 ud = *(const float4*)(xu + di * XSTRIDE + c * 4);
                float4 uk = *(const float4*)(xu + kj * XSTRIDE + c * 4);
                float4 vd = *(const float4*)(xv + di * XSTRIDE + c * 4);
                float4 vk = *(const float4*)(xv + kj * XSTRIDE + c * 4);
                aU.x = fmaf(ud.x, uk.x, aU.x); aU.y = fmaf(ud.y, uk.y, aU.y);
                aU.z = fmaf(ud.z, uk.z, aU.z); aU.w = fmaf(ud.w, uk.w, aU.w);
                aV.x = fmaf(vd.x, vk.x, aV.x); aV.y = fmaf(vd.y, vk.y, aV.y);
                aV.z = fmaf(vd.z, vk.z, aV.z); aV.w = fmaf(vd.w, vk.w, aV.w);
                aC.x = fmaf(vd.x, uk.x, aC.x); aC.y = fmaf(vd.y, uk.y, aC.y);
                aC.z = fmaf(vd.z, uk.z, aC.z); aC.w = fmaf(vd.w, uk.w, aC.w);
            }
            gr[l]      = aU.x + aU.y + aU.z + aU.w;   // Gu
            gr[16 + l] = aV.x + aV.y + aV.z + aV.w;   // Gv
            gr[32 + l] = aC.x + aC.y + aC.z + aC.w;   // C
        }
    }
    __syncthreads();

    // sims for both orientations (G rows == columns by symmetry -> b128 reads)
    float s1 = 0.f, s2 = 0.f;
    if (valid) {
        float4 gsr  = *(const float4*)(gr + kj * 4);        // Gs[kj][:] == Gs[:,kj]
        float4 gtr  = *(const float4*)(gr + 16 + kj * 4);   // Gt[kj][:] == Gt[:,kj]
        float4 crow = *(const float4*)(gr + 32 + kj * 4);   // C[kj][:]  == (C^T)[:,kj]
        float c0 = gr[32 + 0 + kj], c1 = gr[32 + 4 + kj],
              c2 = gr[32 + 8 + kj], c3 = gr[32 + 12 + kj];  // C[:,kj]
        float gss = m1.x * gsr.x + m1.y * gsr.y + m1.z * gsr.z + m1.w * gsr.w;
        float gts = m2.x * c0 + m2.y * c1 + m2.z * c2 + m2.w * c3;
        s1 = 2.0f * (gss - gts);
        float gss2 = m2.x * gtr.x + m2.y * gtr.y + m2.z * gtr.z + m2.w * gtr.w;
        float gts2 = m1.x * crow.x + m1.y * crow.y + m1.z * crow.z + m1.w * crow.w;
        s2 = 2.0f * (gss2 - gts2);
    }

    float* sb = simsb + g * SIMSTRIDE;
    if (valid) {
        sb[l]      = s1;
        sb[16 + l] = s2;
    }
    __syncthreads();

    if (valid) {
        float4 p0 = *(const float4*)(sb + 0),  p1 = *(const float4*)(sb + 4);
        float4 p2 = *(const float4*)(sb + 8),  p3 = *(const float4*)(sb + 12);
        float4 q0 = *(const float4*)(sb + 16), q1 = *(const float4*)(sb + 20);
        float4 q2 = *(const float4*)(sb + 24), q3 = *(const float4*)(sb + 28);
        float a1 = bias, a2 = bias;
        a1 += w0.x*p0.x + w0.y*p0.y + w0.z*p0.z + w0.w*p0.w;
        a1 += w1.x*p1.x + w1.y*p1.y + w1.z*p1.z + w1.w*p1.w;
        a1 += w2.x*p2.x + w2.y*p2.y + w2.z*p2.z + w2.w*p2.w;
        a1 += w3.x*p3.x + w3.y*p3.y + w3.z*p3.z + w3.w*p3.w;
        a2 += w0.x*q0.x + w0.y*q0.y + w0.z*q0.z + w0.w*q0.w;
        a2 += w1.x*q1.x + w1.y*q1.y + w1.z*q1.z + w1.w*q1.w;
        a2 += w2.x*q2.x + w2.y*q2.y + w2.z*q2.z + w2.w*q2.w;
        a2 += w3.x*q3.x + w3.y*q3.y + w3.z*q3.z + w3.w*q3.w;

        out[(size_t)pair * 16 + l] = fast_tanh(a1);   // coalesced 64B/group
        out[(size_t)e2   * 16 + l] = fast_tanh(a2);
    }
}

extern "C" void kernel_launch(void* const* d_in, const int* in_sizes, int n_in,
                              void* d_out, int out_size, void* d_ws, size_t ws_size,
                              hipStream_t stream) {
    const float* x          = (const float*)d_in[0];
    const float* Maps       = (const float*)d_in[1];
    const float* W1         = (const float*)d_in[2];
    const float* b1         = (const float*)d_in[3];
    const int*   edge_index = (const int*)d_in[4];
    const int*   opp_idx    = (const int*)d_in[5];

    const int N     = in_sizes[0] / 128;  // (N, 4, 32)
    const int E     = in_sizes[5];
    const int EHALF = E / 2;

    const size_t gram_bytes = (size_t)N * 16 * sizeof(float);
    const int pair_blocks = (EHALF + GROUPS - 1) / GROUPS;

    if (ws_size >= gram_bytes) {
        float* G = (float*)d_ws;
        const int node_blocks = (N + GROUPS - 1) / GROUPS;
        node_gram_kernel<<<node_blocks, 256, 0, stream>>>(x, G, N);
        sheaf_pair2_kernel<true><<<pair_blocks, 256, 0, stream>>>(
            x, Maps, W1, b1, edge_index, opp_idx, G, (float*)d_out, E, EHALF);
    } else {
        sheaf_pair2_kernel<false><<<pair_blocks, 256, 0, stream>>>(
            x, Maps, W1, b1, edge_index, opp_idx, nullptr, (float*)d_out, E, EHALF);
    }
}

// Round 4
// 62.195 us; speedup vs baseline: 2.6200x; 1.3145x over previous
//
#include <hip/hip_runtime.h>

constexpr int TPB = 256;

__device__ __forceinline__ float fast_tanh(float v) {
    // tanh(x) = 1 - 2/(exp(2x)+1); exact at +/-inf, ~ulp-level error
    float ex = __expf(2.0f * v);
    return 1.0f - 2.0f * __builtin_amdgcn_rcpf(ex + 1.0f);
}

// All-lanes sum within each 16-lane DPP row (rotate-and-add butterfly).
// row_ror:N = dpp_ctrl 0x120|N; GCNDPPCombine fuses mov_dpp+add -> v_add_f32_dpp.
__device__ __forceinline__ float rowsum16(float x) {
    x += __int_as_float(__builtin_amdgcn_update_dpp(0, __float_as_int(x), 0x128, 0xf, 0xf, true)); // ror:8
    x += __int_as_float(__builtin_amdgcn_update_dpp(0, __float_as_int(x), 0x124, 0xf, 0xf, true)); // ror:4
    x += __int_as_float(__builtin_amdgcn_update_dpp(0, __float_as_int(x), 0x122, 0xf, 0xf, true)); // ror:2
    x += __int_as_float(__builtin_amdgcn_update_dpp(0, __float_as_int(x), 0x121, 0xf, 0xf, true)); // ror:1
    return x;
}

// Per undirected pair p (edges e1=p, e2=opp_idx[p], e1=(s->t)):
//   Z = M1*Xs - M2*Xt            (4x32)
//   sims1 = 2*Z*Xs^T             (4x4)
//   sims2 = -2*Z*Xt^T            (4x4)
//   out[e] = tanh(W1 @ vec(sims_e) + b1)
// 16 lanes per pair; lane l owns h-columns {2l, 2l+1}; no LDS, no barriers.
__global__ __launch_bounds__(TPB, 4) void sheaf_dpp_kernel(
    const float* __restrict__ x,          // (N, 4, 32)
    const float* __restrict__ Maps,       // (E, 4, 4)
    const float* __restrict__ W1,         // (16, 16)
    const float* __restrict__ b1,         // (16,)
    const int*   __restrict__ edge_index, // (2, E)
    const int*   __restrict__ opp_idx,    // (E,)
    float*       __restrict__ out,        // (E, 4, 4)
    int E, int EHALF)
{
    const int tid  = threadIdx.x;
    const int l    = tid & 15;                         // lane within 16-lane group
    const int pair = (blockIdx.x * TPB + tid) >> 4;    // group id = pair id
    if (pair >= EHALF) return;                         // whole group uniform

    const int s  = edge_index[pair];
    const int t  = edge_index[E + pair];
    const int e2 = opp_idx[pair];

    // lane's two h-columns of Xs, Xt: 8B per lane, 16 lanes cover each 128B row
    const float* xu = x + (size_t)s * 128 + 2 * l;
    const float* xv = x + (size_t)t * 128 + 2 * l;
    float2 u[4], v[4];
    #pragma unroll
    for (int d = 0; d < 4; ++d) {
        u[d] = *(const float2*)(xu + d * 32);
        v[d] = *(const float2*)(xv + d * 32);
    }

    // full M1, M2 in registers (same 64B lines across the group -> L1 broadcast)
    float4 m1[4], m2[4];
    {
        const float4* M1p = (const float4*)(Maps + (size_t)pair * 16);
        const float4* M2p = (const float4*)(Maps + (size_t)e2   * 16);
        #pragma unroll
        for (int i = 0; i < 4; ++i) { m1[i] = M1p[i]; m2[i] = M2p[i]; }
    }

    // lane-owned W1 row + bias (uniform across groups -> L1)
    float wr[16];
    {
        const float4* Wp = (const float4*)(W1 + l * 16);
        #pragma unroll
        for (int q4 = 0; q4 < 4; ++q4) {
            float4 w = Wp[q4];
            wr[q4 * 4 + 0] = w.x; wr[q4 * 4 + 1] = w.y;
            wr[q4 * 4 + 2] = w.z; wr[q4 * 4 + 3] = w.w;
        }
    }
    const float bias = b1[l];

    // Z rows over lane's 2 columns: Z[i][h] = sum_j M1[i][j]u[j][h] - M2[i][j]v[j][h]
    float2 Z[4];
    #pragma unroll
    for (int i = 0; i < 4; ++i) {
        float zx = m1[i].x * u[0].x;
        zx = fmaf(m1[i].y, u[1].x, zx);
        zx = fmaf(m1[i].z, u[2].x, zx);
        zx = fmaf(m1[i].w, u[3].x, zx);
        zx = fmaf(-m2[i].x, v[0].x, zx);
        zx = fmaf(-m2[i].y, v[1].x, zx);
        zx = fmaf(-m2[i].z, v[2].x, zx);
        zx = fmaf(-m2[i].w, v[3].x, zx);
        float zy = m1[i].x * u[0].y;
        zy = fmaf(m1[i].y, u[1].y, zy);
        zy = fmaf(m1[i].z, u[2].y, zy);
        zy = fmaf(m1[i].w, u[3].y, zy);
        zy = fmaf(-m2[i].x, v[0].y, zy);
        zy = fmaf(-m2[i].y, v[1].y, zy);
        zy = fmaf(-m2[i].z, v[2].y, zy);
        zy = fmaf(-m2[i].w, v[3].y, zy);
        Z[i] = make_float2(zx, zy);
    }

    // per-lane partial sims + DPP all-reduce over the 16-lane group
    // r1[q] = sum_h Z[i][h]*u[k][h] (q=i*4+k); r2[q] = sum_h Z[i][h]*v[k][h]
    float r1[16], r2[16];
    #pragma unroll
    for (int i = 0; i < 4; ++i) {
        #pragma unroll
        for (int k = 0; k < 4; ++k) {
            float a = Z[i].x * u[k].x;
            a = fmaf(Z[i].y, u[k].y, a);
            float c = Z[i].x * v[k].x;
            c = fmaf(Z[i].y, v[k].y, c);
            r1[i * 4 + k] = rowsum16(a);
            r2[i * 4 + k] = rowsum16(c);
        }
    }

    // linear + tanh: a1 = bias + 2*sum_q W[l][q]*r1[q]; a2 = bias - 2*sum_q W[l][q]*r2[q]
    float d1 = 0.f, d2 = 0.f;
    #pragma unroll
    for (int q = 0; q < 16; ++q) {
        d1 = fmaf(wr[q], r1[q], d1);
        d2 = fmaf(-wr[q], r2[q], d2);
    }
    const float a1v = fmaf(2.0f, d1, bias);
    const float a2v = fmaf(2.0f, d2, bias);

    out[(size_t)pair * 16 + l] = fast_tanh(a1v);   // 64B contiguous per group
    out[(size_t)e2   * 16 + l] = fast_tanh(a2v);
}

extern "C" void kernel_launch(void* const* d_in, const int* in_sizes, int n_in,
                              void* d_out, int out_size, void* d_ws, size_t ws_size,
                              hipStream_t stream) {
    const float* x          = (const float*)d_in[0];
    const float* Maps       = (const float*)d_in[1];
    const float* W1         = (const float*)d_in[2];
    const float* b1         = (const float*)d_in[3];
    const int*   edge_index = (const int*)d_in[4];
    const int*   opp_idx    = (const int*)d_in[5];

    const int E     = in_sizes[5];
    const int EHALF = E / 2;

    const int blocks = (EHALF + 15) / 16;  // 16 pairs per 256-thread block
    sheaf_dpp_kernel<<<blocks, TPB, 0, stream>>>(
        x, Maps, W1, b1, edge_index, opp_idx, (float*)d_out, E, EHALF);
}